// Round 1
// 904.540 us; speedup vs baseline: 1.1595x; 1.1595x over previous
//
#include <hip/hip_runtime.h>
#include <math.h>

// ---------------------------------------------------------------------------
// MPNN (NNConv+GRU x3, Set2Set x3, readout).
// R11: k_fused now iterates 4-k chunks (float4 h1), halving the per-edge
// out[src] regather rounds and the barrier count (17->9 iters per split).
// A-frag LDS doubled to two K=128 sub-chunks per iteration; bias+root merged
// into one extra iteration on split 0. h1 stored as float4 chunks (k_h1t).
// ---------------------------------------------------------------------------

typedef _Float16 f16x8 __attribute__((ext_vector_type(8)));
typedef float f32x4 __attribute__((ext_vector_type(4)));

#define BFRAG_TOTAL (66 * 4 * 4 * 64 * 8)  // 540672 halves per array
#define EMAXB 384                          // max edges per 64-node block (LDS)
#define SPLITK 4
#define ITERS 8                            // 4-k iterations per split (32 k)

// graph segment pointers from sorted batch
__global__ void k_gptr(const int* __restrict__ batch, int* __restrict__ gptr,
                       int N, int B) {
  int n = blockIdx.x * 256 + threadIdx.x;
  if (n >= N) return;
  int b = batch[n];
  int bp = (n == 0) ? -1 : batch[n - 1];
  for (int g = bp + 1; g <= b; ++g) gptr[g] = n;
  if (n == N - 1) {
    for (int g = b + 1; g <= B; ++g) gptr[g] = N;
  }
}

__global__ void k_cnt(const int* __restrict__ eidx, int* __restrict__ cnt, int E) {
  int e = blockIdx.x * 256 + threadIdx.x;
  if (e < E) atomicAdd(&cnt[eidx[E + e]], 1);
}

// single-block scan via wave shuffles -> dptr (exclusive CSR pointers)
__global__ __launch_bounds__(1024) void k_scan(const int* __restrict__ cnt,
                                               int* __restrict__ dptr, int N) {
  __shared__ int wsum[16];
  int t = threadIdx.x;
  int lane = t & 63, wid = t >> 6;
  if (t == 0) dptr[0] = 0;
  int running = 0;
  for (int base = 0; base < N; base += 1024) {
    int x = (base + t < N) ? cnt[base + t] : 0;
#pragma unroll
    for (int d = 1; d < 64; d <<= 1) {
      int u = __shfl_up(x, d, 64);
      if (lane >= d) x += u;
    }
    if (lane == 63) wsum[wid] = x;
    __syncthreads();
    if (wid == 0) {
      int y = (lane < 16) ? wsum[lane] : 0;
#pragma unroll
      for (int d = 1; d < 16; d <<= 1) {
        int u = __shfl_up(y, d, 64);
        if (lane >= d) y += u;
      }
      if (lane < 16) wsum[lane] = y;
    }
    __syncthreads();
    int add = running + (wid > 0 ? wsum[wid - 1] : 0);
    if (base + t < N) dptr[base + t + 1] = add + x;
    running += wsum[15];
    __syncthreads();
  }
}

__global__ void k_fill(const int* __restrict__ eidx, const int* __restrict__ dptr,
                       int* __restrict__ fill, int* __restrict__ srcs_s,
                       int* __restrict__ eord, int E) {
  int e = blockIdx.x * 256 + threadIdx.x;
  if (e >= E) return;
  int d = eidx[E + e];
  int pos = dptr[d] + atomicAdd(&fill[d], 1);
  srcs_s[pos] = eidx[e];
  eord[pos] = e;
}

// h4[k>>2][pos] = invdeg(dst) * (h1[pos][4k'], .., h1[pos][4k'+3]) : k-major
__global__ __launch_bounds__(256) void k_h1t(const float* __restrict__ eattr,
                                             const int* __restrict__ eord,
                                             const int* __restrict__ eidx,
                                             const int* __restrict__ cnt,
                                             const float* __restrict__ nn1_w,
                                             const float* __restrict__ nn1_b,
                                             float4* __restrict__ h4, int E,
                                             int Epad) {
  __shared__ float a5[128 * 5];
  __shared__ float w5[128 * 5];
  __shared__ float bb[128];
  __shared__ float idg[128];
  const int t = threadIdx.x;
  const int p0 = blockIdx.x * 128;
  for (int idx = t; idx < 640; idx += 256) w5[idx] = nn1_w[idx];
  if (t < 128) bb[t] = nn1_b[t];
  if (t < 128) {
    int pos = p0 + t;
    if (pos < E) {
      int e = eord[pos];
      const float* a = eattr + (size_t)e * 5;
#pragma unroll
      for (int q = 0; q < 5; ++q) a5[t * 5 + q] = a[q];
      int dg = cnt[eidx[E + e]];
      idg[t] = 1.f / (float)(dg > 1 ? dg : 1);
    } else {
#pragma unroll
      for (int q = 0; q < 5; ++q) a5[t * 5 + q] = 0.f;
      idg[t] = 0.f;
    }
  }
  __syncthreads();
  const int pl = t & 127, jh = (t >> 7) * 64;
  const int pos = p0 + pl;
  if (pos >= E) return;
  float a0 = a5[pl * 5 + 0], a1 = a5[pl * 5 + 1], a2 = a5[pl * 5 + 2],
        a3 = a5[pl * 5 + 3], a4 = a5[pl * 5 + 4];
  float inv = idg[pl];
#pragma unroll 4
  for (int jj = 0; jj < 64; jj += 4) {
    int j = jh + jj;
    float vv[4];
#pragma unroll
    for (int u = 0; u < 4; ++u) {
      const float* wr = &w5[(j + u) * 5];
      vv[u] = fmaxf(bb[j + u] + a0 * wr[0] + a1 * wr[1] + a2 * wr[2] +
                        a3 * wr[3] + a4 * wr[4], 0.f) * inv;
    }
    h4[(size_t)(j >> 2) * Epad + pos] = make_float4(vv[0], vv[1], vv[2], vv[3]);
  }
}

// Pre-split Wbig into fp16 hi/lo in MFMA B-fragment order, one kc per block.
// flat idx = (((kc*4 + w)*4 + c)*64 + lane)*8 + j
__global__ __launch_bounds__(256) void k_bsplit(
    const float* __restrict__ nn2_w, const float* __restrict__ nn2_b,
    const float* __restrict__ root_w, _Float16* __restrict__ Bh,
    _Float16* __restrict__ Bl) {
  __shared__ float lds[4096 * 2];
  const int kc = blockIdx.x;
  const int t = threadIdx.x;
  if (kc < 64) {
    for (int r = t; r < 4096; r += 256) {
      float2 v = *(const float2*)&nn2_w[(size_t)r * 128 + kc * 2];
      lds[r * 2] = v.x;
      lds[r * 2 + 1] = v.y;
    }
  } else if (kc == 64) {
    for (int r = t; r < 4096; r += 256) {
      lds[r * 2] = nn2_b[r];
      lds[r * 2 + 1] = 0.f;
    }
  } else {
    for (int r = t; r < 4096; r += 256) {
      int i = r >> 6, o = r & 63;
      lds[r * 2] = root_w[o * 64 + i];
      lds[r * 2 + 1] = 0.f;
    }
  }
  __syncthreads();
  for (int slot = t; slot < 1024; slot += 256) {
    int lane = slot & 63, c = (slot >> 6) & 3, w = slot >> 8;
    f16x8 ph, pl;
#pragma unroll
    for (int j = 0; j < 8; ++j) {
      int m = w * 32 + ((lane >> 4) << 3) + j;
      int o = c * 16 + (lane & 15);
      int i = m & 63, kl = m >> 6;
      float v = lds[(i * 64 + o) * 2 + kl];
      _Float16 h = (_Float16)v;
      ph[j] = h;
      pl[j] = (_Float16)(v - (float)h);
    }
    size_t base = (((size_t)kc * 4 + w) * 4 + c) * 512 + (size_t)lane * 8;
    *(f16x8*)&Bh[base] = ph;
    *(f16x8*)&Bl[base] = pl;
  }
}

// out = relu(x @ lin0_w^T + lin0_b)
__global__ void k_lin0(const float* __restrict__ x, const float* __restrict__ w,
                       const float* __restrict__ b, float* __restrict__ outn, int N) {
  int gid = blockIdx.x * 256 + threadIdx.x;
  int n = gid >> 6, d = gid & 63;
  if (n >= N) return;
  const float* xr = x + (size_t)n * 11;
  const float* wr = w + d * 11;
  float acc = b[d];
#pragma unroll
  for (int f = 0; f < 11; ++f) acc += xr[f] * wr[f];
  outn[(size_t)n * 64 + d] = fmaxf(acc, 0.f);
}

// ---------------- fused NNConv (M=64, 4-k iterations, split-K x4) ----------
__global__ __launch_bounds__(256, 2) void k_fused(
    const float* __restrict__ outn, const float4* __restrict__ h4,
    const int* __restrict__ dptr, const int* __restrict__ srcs_s,
    const _Float16* __restrict__ Bh, const _Float16* __restrict__ Bl,
    float* __restrict__ agg2, int N, int Epad) {
  __shared__ __align__(16) _Float16 Ah[2 * 16 * 64 * 8];  // 32 KB
  __shared__ __align__(16) _Float16 Al[2 * 16 * 64 * 8];  // 32 KB
  __shared__ __align__(16) float4 hbuf[2][EMAXB];         // 12 KB
  __shared__ int sSrc[EMAXB];                             // 1.5 KB

  const int t = threadIdx.x;
  const int w = t >> 6, lane = t & 63;
  const int nl = t >> 2;   // builder node (0..63)
  const int iq = t & 3;    // i-quarter (16 cols)
  const int split = blockIdx.y;
  const int n0 = blockIdx.x * 64;
  const int n = n0 + nl;
  const bool nvalid = (n < N);
  const int hi_n = (n0 + 64 > N) ? N : (n0 + 64);
  const int p0b = dptr[n0];
  const int p1b = dptr[hi_n];
  const int EB = p1b - p0b;
  const bool useLds = (EB <= EMAXB);
  int p0 = 0, p1 = 0;
  if (nvalid) { p0 = dptr[n]; p1 = dptr[n + 1]; }
  const float inv = 1.f / (float)((p1 - p0) > 1 ? (p1 - p0) : 1);
  const int rt_b = nl >> 4, nm = nl & 15;
  const int EBs = useLds ? EB : 0;

  // ---- stage src list + first h chunk ----
  for (int idx = t; idx < EBs; idx += 256) sSrc[idx] = srcs_s[p0b + idx];
  {
    const float4* hc = h4 + (size_t)(split * ITERS) * Epad;
    for (int idx = t; idx < EBs; idx += 256) hbuf[0][idx] = hc[p0b + idx];
  }
  __syncthreads();

  f32x4 acc[4][4];
#pragma unroll
  for (int a = 0; a < 4; ++a)
#pragma unroll
    for (int c = 0; c < 4; ++c) acc[a][c] = (f32x4)(0.f);

  const int niter = (split == 0) ? (ITERS + 1) : ITERS;
  int cur = 0;
  for (int cc = 0; cc < niter; ++cc) {
    const bool extra = (cc == ITERS);  // bias+root combined (split 0 only)

    // ---- build this thread's 64 A-values (4 kl x 16 i) ----
    float av[4][16];
#pragma unroll
    for (int kl = 0; kl < 4; ++kl)
#pragma unroll
      for (int j = 0; j < 16; ++j) av[kl][j] = 0.f;

    if (!extra) {
      const float4* hc = h4 + (size_t)(split * ITERS + cc) * Epad;
      int pos = p0;
      // 2-edge unrolled: both s-row loads issued independently
      for (; pos + 2 <= p1; pos += 2) {
        int ea = pos - p0b, eb = ea + 1;
        float4 ha = useLds ? hbuf[cur][ea] : hc[pos];
        float4 hb = useLds ? hbuf[cur][eb] : hc[pos + 1];
        int sa = useLds ? sSrc[ea] : srcs_s[pos];
        int sb = useLds ? sSrc[eb] : srcs_s[pos + 1];
        const float4* pa = (const float4*)(outn + (size_t)sa * 64 + iq * 16);
        const float4* pb = (const float4*)(outn + (size_t)sb * 64 + iq * 16);
        float4 a0 = pa[0], a1 = pa[1], a2 = pa[2], a3 = pa[3];
        float4 b0 = pb[0], b1 = pb[1], b2 = pb[2], b3 = pb[3];
        float sva[16] = {a0.x, a0.y, a0.z, a0.w, a1.x, a1.y, a1.z, a1.w,
                         a2.x, a2.y, a2.z, a2.w, a3.x, a3.y, a3.z, a3.w};
        float svb[16] = {b0.x, b0.y, b0.z, b0.w, b1.x, b1.y, b1.z, b1.w,
                         b2.x, b2.y, b2.z, b2.w, b3.x, b3.y, b3.z, b3.w};
#pragma unroll
        for (int j = 0; j < 16; ++j) {
          av[0][j] += ha.x * sva[j] + hb.x * svb[j];
          av[1][j] += ha.y * sva[j] + hb.y * svb[j];
          av[2][j] += ha.z * sva[j] + hb.z * svb[j];
          av[3][j] += ha.w * sva[j] + hb.w * svb[j];
        }
      }
      if (pos < p1) {
        int ea = pos - p0b;
        float4 ha = useLds ? hbuf[cur][ea] : hc[pos];
        int sa = useLds ? sSrc[ea] : srcs_s[pos];
        const float4* pa = (const float4*)(outn + (size_t)sa * 64 + iq * 16);
        float4 a0 = pa[0], a1 = pa[1], a2 = pa[2], a3 = pa[3];
        float sva[16] = {a0.x, a0.y, a0.z, a0.w, a1.x, a1.y, a1.z, a1.w,
                         a2.x, a2.y, a2.z, a2.w, a3.x, a3.y, a3.z, a3.w};
#pragma unroll
        for (int j = 0; j < 16; ++j) {
          av[0][j] += ha.x * sva[j];
          av[1][j] += ha.y * sva[j];
          av[2][j] += ha.z * sva[j];
          av[3][j] += ha.w * sva[j];
        }
      }
    } else {
      // bias chunk (sub0, kl0): A[n] = inv * sum_e s[src];  kl1 = 0
      for (int pos = p0; pos < p1; ++pos) {
        int src = useLds ? sSrc[pos - p0b] : srcs_s[pos];
        const float4* sp = (const float4*)(outn + (size_t)src * 64 + iq * 16);
        float4 s0 = sp[0], s1 = sp[1], s2 = sp[2], s3 = sp[3];
        float sv[16] = {s0.x, s0.y, s0.z, s0.w, s1.x, s1.y, s1.z, s1.w,
                        s2.x, s2.y, s2.z, s2.w, s3.x, s3.y, s3.z, s3.w};
#pragma unroll
        for (int j = 0; j < 16; ++j) av[0][j] += sv[j];
      }
#pragma unroll
      for (int j = 0; j < 16; ++j) av[0][j] *= inv;
      // root chunk (sub1, kl0): A[n] = outn[n];  kl1 = 0
      if (nvalid) {
        const float4* sp = (const float4*)(outn + (size_t)n * 64 + iq * 16);
        float4 s0 = sp[0], s1 = sp[1], s2 = sp[2], s3 = sp[3];
        float sv[16] = {s0.x, s0.y, s0.z, s0.w, s1.x, s1.y, s1.z, s1.w,
                        s2.x, s2.y, s2.z, s2.w, s3.x, s3.y, s3.z, s3.w};
#pragma unroll
        for (int j = 0; j < 16; ++j) av[2][j] = sv[j];
      }
    }

    // ---- split fp16 hi/lo, write A-frag order (two K=128 sub-chunks) ----
#pragma unroll
    for (int kl = 0; kl < 4; ++kl) {
      const float* avp = av[kl];
      const int sub = kl >> 1;
      const int wb = (kl & 1) * 2 + (iq >> 1);
#pragma unroll
      for (int g = 0; g < 2; ++g) {
        int q = (iq & 1) * 2 + g;
        int base = sub * 8192 + ((wb * 4 + rt_b) * 64 + (q << 4) + nm) * 8;
        f16x8 ph, pl;
#pragma unroll
        for (int jj = 0; jj < 8; ++jj) {
          float v = avp[g * 8 + jj];
          _Float16 h = (_Float16)v;
          ph[jj] = h;
          pl[jj] = (_Float16)(v - (float)h);
        }
        *(f16x8*)&Ah[base] = ph;
        *(f16x8*)&Al[base] = pl;
      }
    }
    __syncthreads();

    // ---- MFMA over both sub-chunks + prefetch next h chunk ----
#pragma unroll
    for (int sub = 0; sub < 2; ++sub) {
      const int kco = extra ? (64 + sub) : (split * 16 + cc * 2 + sub);
      f16x8 ah[4], al[4];
#pragma unroll
      for (int rt = 0; rt < 4; ++rt) {
        ah[rt] = *(const f16x8*)&Ah[sub * 8192 + ((w * 4 + rt) * 64 + lane) * 8];
        al[rt] = *(const f16x8*)&Al[sub * 8192 + ((w * 4 + rt) * 64 + lane) * 8];
      }
      if (sub == 0 && cc + 1 < ITERS) {
        const float4* hc = h4 + (size_t)(split * ITERS + cc + 1) * Epad;
        for (int idx = t; idx < EBs; idx += 256) hbuf[cur ^ 1][idx] = hc[p0b + idx];
      }
      size_t bbase = ((size_t)(kco * 4 + w) * 4) * 512;
#pragma unroll
      for (int c = 0; c < 4; ++c) {
        f16x8 bh = *(const f16x8*)&Bh[bbase + c * 512 + lane * 8];
        f16x8 bl = *(const f16x8*)&Bl[bbase + c * 512 + lane * 8];
#pragma unroll
        for (int rt = 0; rt < 4; ++rt) {
          acc[rt][c] = __builtin_amdgcn_mfma_f32_16x16x32_f16(ah[rt], bh, acc[rt][c], 0, 0, 0);
          acc[rt][c] = __builtin_amdgcn_mfma_f32_16x16x32_f16(ah[rt], bl, acc[rt][c], 0, 0, 0);
          acc[rt][c] = __builtin_amdgcn_mfma_f32_16x16x32_f16(al[rt], bh, acc[rt][c], 0, 0, 0);
        }
      }
    }
    __syncthreads();
    if (cc + 1 < ITERS) cur ^= 1;
  }

  // ---- epilogue: atomic accumulate (split-K) ----
  const int qrow = (lane >> 4) * 4, col = lane & 15;
#pragma unroll
  for (int rt = 0; rt < 4; ++rt) {
#pragma unroll
    for (int r = 0; r < 4; ++r) {
      int nn = n0 + rt * 16 + qrow + r;
      if (nn < N) {
        float* ap = agg2 + (size_t)nn * 64 + col;
#pragma unroll
        for (int c = 0; c < 4; ++c) atomicAdd(ap + c * 16, acc[rt][c][r]);
      }
    }
  }
}

// GRU step (16 nodes/block, 4 per wave): m = relu(agg2+conv_b); out <- GRU
__global__ __launch_bounds__(256) void k_gru(
    const float* __restrict__ agg2, const float* __restrict__ conv_b,
    const float* __restrict__ gw_ih, const float* __restrict__ gw_hh,
    const float* __restrict__ gb_ih, const float* __restrict__ gb_hh,
    float* __restrict__ outn, int N) {
  __shared__ float wT[32 * 385];
  const int t = threadIdx.x;
  const int wv = t >> 6, d = t & 63;
  const int nbase = blockIdx.x * 16 + wv * 4;
  float m_d[4], h_d[4];
  bool act[4];
#pragma unroll
  for (int j = 0; j < 4; ++j) {
    int n = nbase + j;
    act[j] = (n < N);
    m_d[j] = act[j] ? fmaxf(agg2[(size_t)n * 64 + d] + conv_b[d], 0.f) : 0.f;
    h_d[j] = act[j] ? outn[(size_t)n * 64 + d] : 0.f;
  }
  float ir[4] = {0, 0, 0, 0}, iz[4] = {0, 0, 0, 0}, in_[4] = {0, 0, 0, 0};
  float hr[4] = {0, 0, 0, 0}, hz[4] = {0, 0, 0, 0}, hn[4] = {0, 0, 0, 0};
  for (int half = 0; half < 2; ++half) {
    __syncthreads();
    for (int idx = t; idx < 192 * 32; idx += 256) {
      int g = idx >> 5, kl = idx & 31;
      wT[kl * 385 + g] = gw_ih[g * 64 + half * 32 + kl];
      wT[kl * 385 + 192 + g] = gw_hh[g * 64 + half * 32 + kl];
    }
    __syncthreads();
#pragma unroll
    for (int kl = 0; kl < 32; ++kl) {
      int k = half * 32 + kl;
      const float* row = &wT[kl * 385];
      float r0 = row[d], r1 = row[64 + d], r2 = row[128 + d];
      float r3 = row[192 + d], r4 = row[256 + d], r5 = row[320 + d];
#pragma unroll
      for (int j = 0; j < 4; ++j) {
        float mk = __shfl(m_d[j], k);
        float hk = __shfl(h_d[j], k);
        ir[j] += r0 * mk;
        iz[j] += r1 * mk;
        in_[j] += r2 * mk;
        hr[j] += r3 * hk;
        hz[j] += r4 * hk;
        hn[j] += r5 * hk;
      }
    }
  }
#pragma unroll
  for (int j = 0; j < 4; ++j) {
    if (act[j]) {
      int n = nbase + j;
      float r = 1.f / (1.f + expf(-(ir[j] + gb_ih[d] + hr[j] + gb_hh[d])));
      float z = 1.f / (1.f + expf(-(iz[j] + gb_ih[64 + d] + hz[j] + gb_hh[64 + d])));
      float nn = tanhf(in_[j] + gb_ih[128 + d] + r * (hn[j] + gb_hh[128 + d]));
      outn[(size_t)n * 64 + d] = (1.f - z) * nn + z * h_d[j];
    }
  }
}

// ---------------- fused Set2Set (3 steps) + readout, one block per graph ---
__global__ __launch_bounds__(256) void k_s2s(
    const float* __restrict__ outn, const int* __restrict__ gptr,
    const float* __restrict__ w_ih, const float* __restrict__ w_hh,
    const float* __restrict__ b_ih, const float* __restrict__ b_hh,
    const float* __restrict__ w1, const float* __restrict__ b1,
    const float* __restrict__ w2, const float* __restrict__ b2,
    float* __restrict__ y) {
  __shared__ float q[128];
  __shared__ float hsL[64];
  __shared__ float csL[64];
  __shared__ float gate[256];
  __shared__ float red[4][66];  // per-wave: m, den, racc[64]
  const int b = blockIdx.x, t = threadIdx.x;
  const int wv = t >> 6, d = t & 63;
  const int n0 = gptr[b], n1 = gptr[b + 1];
  if (t < 128) q[t] = 0.f;
  if (t < 64) { hsL[t] = 0.f; csL[t] = 0.f; }
  __syncthreads();

  for (int step = 0; step < 3; ++step) {
    float acc = b_ih[t] + b_hh[t];
    const float* wi = w_ih + t * 128;
    const float* wh = w_hh + t * 64;
#pragma unroll 4
    for (int k = 0; k < 128; ++k) acc += wi[k] * q[k];
#pragma unroll 4
    for (int k = 0; k < 64; ++k) acc += wh[k] * hsL[k];
    gate[t] = acc;
    __syncthreads();
    if (t < 64) {
      float ig = gate[t], fg = gate[64 + t], gg = gate[128 + t],
            og = gate[192 + t];
      float c = csL[t];
      float si = 1.f / (1.f + expf(-ig));
      float sf = 1.f / (1.f + expf(-fg));
      float so = 1.f / (1.f + expf(-og));
      float cn = sf * c + si * tanhf(gg);
      csL[t] = cn;
      hsL[t] = so * tanhf(cn);
    }
    __syncthreads();

    float qd = hsL[d];
    float mx = -3.4e38f, den = 0.f, racc = 0.f;
    for (int nn = n0 + wv; nn < n1; nn += 4) {
      float od = outn[(size_t)nn * 64 + d];
      float v = od * qd;
      for (int s = 32; s > 0; s >>= 1) v += __shfl_xor(v, s);
      float mnew = fmaxf(mx, v);
      float scale = expf(mx - mnew);
      float a = expf(v - mnew);
      den = den * scale + a;
      racc = racc * scale + a * od;
      mx = mnew;
    }
    if (d == 0) { red[wv][0] = mx; red[wv][1] = den; }
    red[wv][2 + d] = racc;
    __syncthreads();
    if (t < 64) {
      float M = fmaxf(fmaxf(red[0][0], red[1][0]), fmaxf(red[2][0], red[3][0]));
      float dd = 0.f, rr = 0.f;
#pragma unroll
      for (int ww = 0; ww < 4; ++ww) {
        float sc = expf(red[ww][0] - M);
        dd += red[ww][1] * sc;
        rr += red[ww][2 + t] * sc;
      }
      float r = (dd > 0.f) ? rr / dd : 0.f;
      q[t] = hsL[t];
      q[64 + t] = r;
    }
    __syncthreads();
  }

  if (t < 64) {
    float acc = b1[t];
    const float* wr = w1 + t * 128;
#pragma unroll 4
    for (int k = 0; k < 128; ++k) acc += wr[k] * q[k];
    acc = fmaxf(acc, 0.f) * w2[t];
    for (int s = 32; s > 0; s >>= 1) acc += __shfl_xor(acc, s);
    if (t == 0) y[b] = acc + b2[0];
  }
}

extern "C" void kernel_launch(void* const* d_in, const int* in_sizes, int n_in,
                              void* d_out, int out_size, void* d_ws,
                              size_t ws_size, hipStream_t stream) {
  (void)n_in; (void)out_size; (void)ws_size;
  const float* x      = (const float*)d_in[0];
  const int*   eidx   = (const int*)d_in[1];
  const float* eattr  = (const float*)d_in[2];
  const int*   batch  = (const int*)d_in[3];
  const float* lin0_w = (const float*)d_in[4];
  const float* lin0_b = (const float*)d_in[5];
  const float* nn1_w  = (const float*)d_in[6];
  const float* nn1_b  = (const float*)d_in[7];
  const float* nn2_w  = (const float*)d_in[8];
  const float* nn2_b  = (const float*)d_in[9];
  const float* root_w = (const float*)d_in[10];
  const float* conv_b = (const float*)d_in[11];
  const float* gw_ih  = (const float*)d_in[12];
  const float* gw_hh  = (const float*)d_in[13];
  const float* gb_ih  = (const float*)d_in[14];
  const float* gb_hh  = (const float*)d_in[15];
  const float* lw_ih  = (const float*)d_in[16];
  const float* lw_hh  = (const float*)d_in[17];
  const float* lb_ih  = (const float*)d_in[18];
  const float* lb_hh  = (const float*)d_in[19];
  const float* lin1_w = (const float*)d_in[20];
  const float* lin1_b = (const float*)d_in[21];
  const float* lin2_w = (const float*)d_in[22];
  const float* lin2_b = (const float*)d_in[23];

  const int N = in_sizes[0] / 11;
  const int E = in_sizes[1] / 2;
  const int B = 512;
  const int Epad = (E + 127) & ~127;

  size_t off = 0;
  auto bump = [&](size_t bytes) {
    size_t o = off;
    off += (bytes + 255) & ~(size_t)255;
    return o;
  };
  char* base = (char*)d_ws;
  float*     outn   = (float*)(base + bump((size_t)N * 64 * 4));
  float*     agg2   = (float*)(base + bump((size_t)N * 64 * 4));
  float4*    h1p4   = (float4*)(base + bump((size_t)32 * Epad * 16));
  _Float16*  Bh     = (_Float16*)(base + bump((size_t)BFRAG_TOTAL * 2));
  _Float16*  Bl     = (_Float16*)(base + bump((size_t)BFRAG_TOTAL * 2));
  int*       cnt    = (int*)(base + bump((size_t)2 * N * 4));  // cnt + fill
  int*       fill   = cnt + N;
  int*       dptr   = (int*)(base + bump((size_t)(N + 1) * 4));
  int*       srcs_s = (int*)(base + bump((size_t)E * 4));
  int*       eord   = (int*)(base + bump((size_t)E * 4));
  int*       gptr   = (int*)(base + bump((size_t)(B + 1) * 4));

  hipMemsetAsync(cnt, 0, (size_t)2 * N * 4, stream);

  k_gptr<<<(N + 255) / 256, 256, 0, stream>>>(batch, gptr, N, B);
  k_cnt<<<(E + 255) / 256, 256, 0, stream>>>(eidx, cnt, E);
  k_scan<<<1, 1024, 0, stream>>>(cnt, dptr, N);
  k_fill<<<(E + 255) / 256, 256, 0, stream>>>(eidx, dptr, fill, srcs_s, eord, E);
  k_h1t<<<(E + 127) / 128, 256, 0, stream>>>(eattr, eord, eidx, cnt, nn1_w,
                                             nn1_b, h1p4, E, Epad);
  k_bsplit<<<66, 256, 0, stream>>>(nn2_w, nn2_b, root_w, Bh, Bl);
  k_lin0<<<(N * 64 + 255) / 256, 256, 0, stream>>>(x, lin0_w, lin0_b, outn, N);

  const int NBLK = (N + 63) / 64;
  for (int it = 0; it < 3; ++it) {
    hipMemsetAsync(agg2, 0, (size_t)N * 64 * 4, stream);
    k_fused<<<dim3(NBLK, SPLITK), 256, 0, stream>>>(outn, h1p4, dptr, srcs_s,
                                                    Bh, Bl, agg2, N, Epad);
    k_gru<<<(N + 15) / 16, 256, 0, stream>>>(agg2, conv_b, gw_ih, gw_hh, gb_ih,
                                             gb_hh, outn, N);
  }

  k_s2s<<<B, 256, 0, stream>>>(outn, gptr, lw_ih, lw_hh, lb_ih, lb_hh, lin1_w,
                               lin1_b, lin2_w, lin2_b, (float*)d_out);
}